// Round 1
// 387.172 us; speedup vs baseline: 1.2339x; 1.2339x over previous
//
#include <hip/hip_runtime.h>
#include <cfloat>

#define NROW   256      // B*E rows
#define RLEN   65536    // N*N elements per row
#define TPB    1024
#define VPT    64       // register-resident values per thread (64*1024 = RLEN)
#define REGS   8        // candidate slots per thread (values in VGPRs)
#define MAXC   (TPB*REGS)   // 8192
#define NITER  64       // scan length (local_k)
#define KSEL   64       // top-k
#define THETA_OFF 8.0f  // initial candidate threshold: M0 - 8.0
#define TCAP   256      // tie-list capacity
#define LN_TGT 7.6246f  // ln(2048): adaptive-theta target count

// R10 = R9 scan/select verbatim + memory/threshold restructure:
// (1) SINGLE global pass: v[64] lives in VGPRs. Ownership remapped to
//     p = tid + 1024*s so score loads stride 16B lane-to-lane (wave spans
//     1KB = 16 lines/instr vs R9's 4KB = 64 lines/instr) and gumbel loads
//     are dword-coalesced. R9 traversed the full 134MB a second time just
//     to collect candidates; collection/M0/Mu/U now come from registers.
// (2) Adaptive theta via exact register recount (<=12 cheap probes, ln-step
//     toward count 2048). cnt = #{v >= M0-8} is ~ e^8 * Exp(1) distributed:
//     6.4% of rows overflowed MAXC in R9 and paid a full third global pass
//     (theta += 1 retry); with 256 rows the wall clock always contained
//     stragglers. Now every row lands in cnt in [64, 8128] with zero extra
//     global traffic, and count==append predicate identity makes overflow
//     impossible. theta stays >= ln(2048/64)=3.5 below the rank-64 value,
//     so the (kept, verbatim) expansion net's trigger margin is preserved.
// (3) Expansion path (rare) re-reads global with the same mapping -> v is
//     bit-identical; rolled loop to keep I-cache small.
// LDS kept ~82KB so only 1 block/CU fits (grid spreads over all 256 CUs).
__global__ void __launch_bounds__(TPB)
GumbelSampler_2482491097709_kernel(const float* __restrict__ scores,
                                   const float* __restrict__ gumbel,
                                   float* __restrict__ out)
{
    __shared__ float s_A[16];       // scan max partials
    __shared__ float s_B[16];       // scan sum partials
    __shared__ float s_EA[16];      // collect/expansion max partials
    __shared__ float s_EB[16];      // collect/expansion sum partials
    __shared__ int   s_IC[16];      // adaptive-theta count partials
    __shared__ float s_mx[NITER];   // recorded 10*max(flat_t) (for backfill)
    __shared__ float s_rcp[NITER];  // recorded 1/S_t (for backfill)
    __shared__ int   s_cnt;
    __shared__ int   s_selB;        // histogram: found bin (per pass)
    __shared__ int   s_selR;        // histogram: residual rank (per pass)
    __shared__ int   s_tcnt;
    __shared__ int   s_tie[TCAP];
    __shared__ int   s_hist[4096];  // 16 KB: radix passes use <=2048 bins;
                                    // oversized on purpose (LDS > 80 KB)
    __shared__ int   cand_idx[MAXC];
    __shared__ float cand_kv[MAXC]; // staging value, then accumulated khot

    const int tid  = threadIdx.x;
    const int lane = tid & 63;
    const int wid  = tid >> 6;

    // XCD swizzle: co-locate the 4 e-blocks of each b on one XCD (perf only).
    const int q    = blockIdx.x;
    const int xcd  = q & 7;
    const int slot = q >> 3;
    const int b    = xcd * 8 + (slot & 7);
    const int e    = slot >> 3;
    const int r    = b * 4 + e;

    const float* __restrict__ sr = scores + (size_t)b * (RLEN * 4) + e;
    const float* __restrict__ gr = gumbel + (size_t)r * RLEN;

    // ---- Single global read: v[s] for positions p = tid + TPB*s ----
    float v[VPT];
#pragma unroll
    for (int s = 0; s < VPT; ++s) {
        int p = tid + TPB * s;
        v[s] = sr[(size_t)p * 4] + gr[p];
    }

    // ---- Block max M0 (exact, order-independent) ----
    float lm = -FLT_MAX;
#pragma unroll
    for (int s = 0; s < VPT; ++s) lm = fmaxf(lm, v[s]);
#pragma unroll
    for (int o = 32; o; o >>= 1) lm = fmaxf(lm, __shfl_xor(lm, o));
    if (lane == 0) s_A[wid] = lm;
    __syncthreads();
    float M0 = s_A[0];
#pragma unroll
    for (int w = 1; w < 16; ++w) M0 = fmaxf(M0, s_A[w]);   // uniform
    const float C = M0 * 10.0f;          // anchor for the frozen-tail U only

    // ---- Adaptive theta: exact count from registers, ln-step to ~2048 ----
    // count predicate (v[s] >= theta) is IDENTICAL to the append predicate,
    // so the final cnt equals the accepted count exactly: no overflow path.
    float theta = M0 - THETA_OFF;
    for (int probe = 0; probe < 12; ++probe) {
        int lc = 0;
#pragma unroll
        for (int s = 0; s < VPT; ++s) lc += (v[s] >= theta) ? 1 : 0;
#pragma unroll
        for (int o = 32; o; o >>= 1) lc += __shfl_xor(lc, o);
        if (lane == 0) s_IC[wid] = lc;
        __syncthreads();
        int cc = 0;
#pragma unroll
        for (int w = 0; w < 16; ++w) cc += s_IC[w];        // uniform (int)
        __syncthreads();                 // s_IC reads done before next write
        if (cc > MAXC - 64)      theta += __logf((float)cc) - LN_TGT;  // up
        else if (cc < KSEL)      theta -= LN_TGT - __logf((float)(cc < 1 ? 1 : cc));
        else break;                      // 64 <= cnt <= 8128: accept
    }

    // ---- Collect candidates + frozen-tail Mu/U (from registers) ----
    if (tid == 0) s_cnt = 0;
    __syncthreads();
    {
        float mu = -FLT_MAX, u = 0.f;
#pragma unroll
        for (int s = 0; s < VPT; ++s) {
            float val = v[s];
            if (val >= theta) {
                int sl = atomicAdd(&s_cnt, 1);
                if (sl < MAXC) { cand_idx[sl] = tid + TPB * s; cand_kv[sl] = val; }
            } else {
                mu = fmaxf(mu, val);
                u += __expf(fmaf(val, 10.f, -C));
            }
        }
#pragma unroll
        for (int o = 32; o; o >>= 1) {
            mu = fmaxf(mu, __shfl_xor(mu, o));
            u += __shfl_xor(u, o);
        }
        if (lane == 0) { s_EA[wid] = mu; s_EB[wid] = u; }
    }
    __syncthreads();                     // staging + partials visible
    int cnt = s_cnt;
    float Mu = -FLT_MAX, U = 0.f;
#pragma unroll
    for (int w = 0; w < 16; ++w) { Mu = fmaxf(Mu, s_EA[w]); U += s_EB[w]; }
    // v[] is dead past this point on the hot path (frees 64 VGPRs for scan);
    // the rare expansion path re-reads global with identical arithmetic.

    // ---- Owner pull: value -> rcur (VGPR); kv slot becomes khot acc = 0 ----
    float rcur[REGS];
#pragma unroll
    for (int j = 0; j < REGS; ++j) {
        int sl = tid + TPB * j;
        if (sl < cnt) {
            rcur[j] = cand_kv[sl];       // appender's write, barrier'd above
            cand_kv[sl] = 0.f;           // same-thread from here on
        } else rcur[j] = 0.f;
    }

    // ---- Scan: 64 iterations, R4-verbatim trajectory arithmetic ----
    bool  noexp = false;
    float pmx = 0.f, prcp = 0.f, pt2 = 0.f;
    for (int t = 0; t < NITER; ++t) {
        // Phase A: apply iteration t-1's onehot + correction, track max.
        // kh and correction both gated on y > pt2 (skip exact for cur;
        // kh skip error <= 1.5e-8/iter vs >=1e-4 rank gap).
        float lmx = -FLT_MAX;
        if (t == 0) {
#pragma unroll
            for (int j = 0; j < REGS; ++j)
                if (tid + TPB * j < cnt) lmx = fmaxf(lmx, rcur[j]);
        } else {
#pragma unroll
            for (int j = 0; j < REGS; ++j) {
                int sl = tid + TPB * j;
                if (sl < cnt) {
                    float cur = rcur[j];
                    float y = fmaf(cur, 10.f, -pmx);
                    if (y > pt2) {
                        float o = __expf(y) * prcp;
                        cand_kv[sl] += o;               // same-thread LDS RMW
                        cur += __logf(fmaxf(1.f - o, FLT_MIN));
                        rcur[j] = cur;
                    }
                    lmx = fmaxf(lmx, cur);
                }
            }
        }
#pragma unroll
        for (int o = 32; o; o >>= 1) lmx = fmaxf(lmx, __shfl_xor(lmx, o));
        if (lane == 0) s_A[wid] = lmx;
        __syncthreads();
        float gm = s_A[0];
#pragma unroll
        for (int w = 1; w < 16; ++w) gm = fmaxf(gm, s_A[w]);   // uniform
        const float mx = fmaxf(gm, Mu) * 10.f;   // includes frozen-tail max

        // Phase B: sumexp at anchor mx (verbatim — full sum, fresh anchor)
        float ls = 0.f;
#pragma unroll
        for (int j = 0; j < REGS; ++j)
            if (tid + TPB * j < cnt) ls += __expf(fmaf(rcur[j], 10.f, -mx));
#pragma unroll
        for (int o = 32; o; o >>= 1) ls += __shfl_xor(ls, o);
        if (lane == 0) s_B[wid] = ls;
        __syncthreads();
        float S = 0.f;
#pragma unroll
        for (int w = 0; w < 16; ++w) S += s_B[w];              // uniform order
        if (U > 0.f) S += __expf(C - mx + __logf(U));  // frozen tail, log-space
        float lnse = __logf(S);
        float rcp  = 1.f / S;
        float t2   = lnse - 18.03f;
        if (tid == 0) { s_mx[t] = mx; s_rcp[t] = rcp; }  // history for backfill
        pmx = mx; prcp = rcp; pt2 = t2;

        // Expansion trigger (uniform): non-candidate onehot_t > 2^-25 requires
        // 10*Mu > Lse_t - 17.33; fire 2.67 early. Lands before iteration t+1
        // applies rcp_t corrections -> exact.
        if (!noexp && t < NITER - 1) {
            float Lse = mx + lnse;
            if (10.f * Mu > Lse - 20.f) {
                float thOld = theta;
                float thN   = (Lse - 26.f) * 0.1f;
                int   oldc  = cnt;
                float mu2 = -FLT_MAX, u2 = 0.f;
#pragma unroll 4
                for (int s = 0; s < VPT; ++s) {
                    int p = tid + TPB * s;
                    float val = sr[(size_t)p * 4] + gr[p];   // bit-identical v
                    if (val < thOld) {
                        if (val >= thN) {
                            int sl = atomicAdd(&s_cnt, 1);
                            if (sl < MAXC) {
                                cand_idx[sl] = p;
                                cand_kv[sl]  = val;   // staged, bit-frozen
                            }
                        } else {
                            mu2 = fmaxf(mu2, val);
                            u2 += __expf(fmaf(val, 10.f, -C));
                        }
                    }
                }
#pragma unroll
                for (int o = 32; o; o >>= 1) {
                    mu2 = fmaxf(mu2, __shfl_xor(mu2, o));
                    u2 += __shfl_xor(u2, o);
                }
                if (lane == 0) { s_EA[wid] = mu2; s_EB[wid] = u2; }
                __syncthreads();         // appends + partials visible
                int newc = s_cnt;
                if (newc > MAXC) {
                    if (tid == 0) s_cnt = oldc;  // discard partial appends
                    noexp = true;                // uniform; never expand again
                } else {
                    float m2 = -FLT_MAX, uu = 0.f;
#pragma unroll
                    for (int w = 0; w < 16; ++w) {
                        m2 = fmaxf(m2, s_EA[w]); uu += s_EB[w];
                    }
                    Mu = m2; U = uu; theta = thN;
                    // owners pull new slots: value -> rcur, kv -> khot backfill
#pragma unroll
                    for (int j = 0; j < REGS; ++j) {
                        int sl = tid + TPB * j;
                        if (sl >= oldc && sl < newc) {
                            float vv = cand_kv[sl];
                            rcur[j] = vv;
                            float kb = 0.f;   // onehots tt<t (each < e^-20)
                            for (int tt = 0; tt < t; ++tt)
                                kb += __expf(fmaf(vv, 10.f, -s_mx[tt])) * s_rcp[tt];
                            cand_kv[sl] = kb;
                        }
                    }
                    cnt = newc;
                }
            }
        }
    }
    // final iteration's onehot (t = NITER-1): accumulate only (gated, tiny-skip)
#pragma unroll
    for (int j = 0; j < REGS; ++j) {
        int sl = tid + TPB * j;
        if (sl < cnt) {
            float y = fmaf(rcur[j], 10.f, -pmx);
            if (y > pt2) cand_kv[sl] += __expf(y) * prcp;
        }
    }
    __syncthreads();       // all khot final & visible to all threads

    // ---- Radix-histogram top-64 (exact, jax top_k tie-break) ----
    // Keys = __float_as_uint(khot), khot >= 0 -> bit order == value order.
    // kh == 0 slots are excluded (>=64 positive khot guaranteed: the true
    // top-64 each have khot >= 1.5e-5, far above the accumulate gate).
    // Pass bins: [31:21] (2048), [20:10] (2048), [9:0] (1024). After each
    // pass, wave 0 finds the bin holding descending-rank Rrem and the
    // residual rank within it. After pass 3: K* = exact 64th-largest key,
    // Rrem = number of ties (== K*) to take, smallest index first.
    unsigned prefix = 0;
    int Rrem = KSEL;
    for (int pass = 0; pass < 3; ++pass) {
        const int nbins = (pass == 2) ? 1024 : 2048;
        for (int i = tid; i < nbins; i += TPB) s_hist[i] = 0;
        __syncthreads();
#pragma unroll
        for (int j = 0; j < REGS; ++j) {
            int sl = tid + TPB * j;
            if (sl < cnt) {
                unsigned key = __float_as_uint(cand_kv[sl]);
                if (key != 0u) {
                    bool m; int bin;
                    if (pass == 0)      { m = true;                     bin = key >> 21; }
                    else if (pass == 1) { m = (key >> 21) == prefix;    bin = (key >> 10) & 2047; }
                    else                { m = (key >> 10) == prefix;    bin = key & 1023; }
                    if (m) atomicAdd(&s_hist[bin], 1);
                }
            }
        }
        __syncthreads();
        if (wid == 0) {
            int Rl = Rrem, found = -1;
            const int nch = nbins >> 6;
            for (int c = 0; c < nch && found < 0; ++c) {
                int bin = nbins - 1 - (c * 64 + lane);   // descending bins
                int h = s_hist[bin];
                int cum = h;
#pragma unroll
                for (int s2 = 1; s2 < 64; s2 <<= 1) {
                    int vv = __shfl_up(cum, s2);
                    if (lane >= s2) cum += vv;
                }
                unsigned long long mb = __ballot(cum >= Rl);
                if (mb) {
                    int fl = __ffsll(mb) - 1;            // first (highest) bin
                    int cumex = __shfl(cum, fl) - __shfl(h, fl);
                    found = nbins - 1 - (c * 64 + fl);
                    Rl -= cumex;                          // rank inside bin
                } else {
                    Rl -= __shfl(cum, 63);                // whole chunk above
                }
            }
            if (lane == 0) { s_selB = found; s_selR = Rl; }
        }
        __syncthreads();
        prefix = (prefix << ((pass == 2) ? 10 : 11)) | (unsigned)s_selB;
        Rrem = s_selR;
    }
    const unsigned Kstar = prefix;       // exact 64th-largest key
    const int need = Rrem;               // ties to take (>= 1)

    // ---- Emit: all key > K*; collect ties == K* ----
    if (tid == 0) s_tcnt = 0;
    __syncthreads();
#pragma unroll
    for (int j = 0; j < REGS; ++j) {
        int sl = tid + TPB * j;
        if (sl < cnt) {
            float kh = cand_kv[sl];
            unsigned key = __float_as_uint(kh);
            if (key > Kstar) {
                int p = cand_idx[sl];
                out[((size_t)b * RLEN + (size_t)p) * 4 + e] = (1.f - kh) + kh;
            } else if (key == Kstar) {
                int tp = atomicAdd(&s_tcnt, 1);
                if (tp < TCAP) s_tie[tp] = cand_idx[sl];
            }
        }
    }
    __syncthreads();
    // wave 0 picks the `need` smallest tie indices (typically need==1, T==1)
    if (wid == 0) {
        int T = s_tcnt < TCAP ? s_tcnt : TCAP;
        float kv = __uint_as_float(Kstar);
        float ov = (1.f - kv) + kv;
        for (int rdone = 0; rdone < need; ++rdone) {
            int bi = 0x7fffffff, bp = -1;
            for (int i = lane; i < T; i += 64) {
                int vv = s_tie[i];
                if (vv < bi) { bi = vv; bp = i; }
            }
#pragma unroll
            for (int s2 = 32; s2; s2 >>= 1) {
                int oi = __shfl_xor(bi, s2);
                int op = __shfl_xor(bp, s2);
                if (oi < bi) { bi = oi; bp = op; }
            }
            if (lane == 0 && bi != 0x7fffffff) {
                out[((size_t)b * RLEN + (size_t)bi) * 4 + e] = ov;
                s_tie[bp] = 0x7fffffff;      // remove; wave-local LDS is ordered
            }
        }
    }
}

extern "C" void kernel_launch(void* const* d_in, const int* in_sizes, int n_in,
                              void* d_out, int out_size, void* d_ws, size_t ws_size,
                              hipStream_t stream) {
    const float* scores = (const float*)d_in[0];   // [B=64, N=256, N=256, E=4] f32
    const float* gumbel = (const float*)d_in[1];   // [B*E=256, N*N=65536] f32
    float* out = (float*)d_out;                    // [B, N, N, E] f32

    // DMA zero-fill (graph-capturable async memset), then sparse scatter.
    hipMemsetAsync(d_out, 0, (size_t)out_size * sizeof(float), stream);
    GumbelSampler_2482491097709_kernel<<<NROW, TPB, 0, stream>>>(scores, gumbel, out);
}

// Round 2
// 369.653 us; speedup vs baseline: 1.2924x; 1.0474x over previous
//
#include <hip/hip_runtime.h>
#include <cfloat>

#define NROW   256      // B*E rows
#define RLEN   65536    // N*N elements per row
#define TPB    1024
#define VPT    64       // register-resident values per thread (64*1024 = RLEN)
#define REGS   8        // candidate slots per thread (values in VGPRs)
#define MAXC   (TPB*REGS)   // 8192
#define NITER  64       // scan length (local_k)
#define KSEL   64       // top-k
#define THETA_OFF 8.0f  // initial candidate threshold: M0 - 8.0
#define TCAP   256      // tie-list capacity
#define LN_TGT 7.6246f  // ln(2048): adaptive-theta target count
#define AGUARD 40.0f    // stale-anchor guard: redo sum if anc - fresh_max*10 > 40

// R11 = R10 + two structural fixes driven by the R10 counters:
// (1) VGPR_Count stayed 64 in R10 => the compiler REMATERIALIZED v[64] as
//     global reloads (launch_bounds without min-waves let it target a
//     64-VGPR/8-wave budget). Fix: __launch_bounds__(1024,4) (the launchable
//     max is 4 waves/EU -> 128 VGPRs anyway) + asm-pin each v[s] so reloads
//     are impossible. One cold gather traversal instead of ~3.
// (2) Scan fused to ONE barrier + ONE butterfly per iteration. Output is
//     (1-kh)+kh == exactly 1.0f for any kh in [0,2) (Sterbenz / rounding
//     absorption), so absmax==0 depends ONLY on the selected set (rank gaps
//     ~1e-4): bit-exact sum order is not required, khot needs ~1e-5.
//     Sumexp is anchored at the PREVIOUS iteration's max (block-uniform =>
//     wave partials add directly); max+sum share one interleaved butterfly;
//     partial arrays are ping-pong double-buffered (one __syncthreads/iter).
//     Stale-anchor underflow guard: if anc - 10*fresh_max > 40 (Exp-tail
//     event, ~2% of rows once, but >87 WOULD eventually nuke S to 0), redo
//     the sum at the fresh anchor (uniform branch, one extra barrier).
// Everything else (adaptive theta, collect, expansion net, radix top-64,
// tie-break emit) is R10-verbatim. LDS ~84 KB keeps 1 block/CU.
__global__ void __launch_bounds__(TPB, 4)
GumbelSampler_2482491097709_kernel(const float* __restrict__ scores,
                                   const float* __restrict__ gumbel,
                                   float* __restrict__ out)
{
    __shared__ float s_Am[2][16];   // fused scan: max partials (ping-pong)
    __shared__ float s_Bs[2][16];   // fused scan: sum partials (ping-pong)
    __shared__ float s_R[16];       // guard-redo sum partials
    __shared__ float s_EA[16];      // collect/expansion max partials
    __shared__ float s_EB[16];      // collect/expansion sum partials
    __shared__ int   s_IC[16];      // adaptive-theta count partials
    __shared__ float s_mx[NITER];   // recorded anchor a_t (for backfill)
    __shared__ float s_rcp[NITER];  // recorded 1/S_t at a_t (for backfill)
    __shared__ int   s_cnt;
    __shared__ int   s_selB;        // histogram: found bin (per pass)
    __shared__ int   s_selR;        // histogram: residual rank (per pass)
    __shared__ int   s_tcnt;
    __shared__ int   s_tie[TCAP];
    __shared__ int   s_hist[4096];  // 16 KB: radix passes use <=2048 bins;
                                    // oversized on purpose (LDS > 80 KB)
    __shared__ int   cand_idx[MAXC];
    __shared__ float cand_kv[MAXC]; // staging value, then accumulated khot

    const int tid  = threadIdx.x;
    const int lane = tid & 63;
    const int wid  = tid >> 6;

    // XCD swizzle: co-locate the 4 e-blocks of each b on one XCD (perf only).
    const int q    = blockIdx.x;
    const int xcd  = q & 7;
    const int slot = q >> 3;
    const int b    = xcd * 8 + (slot & 7);
    const int e    = slot >> 3;
    const int r    = b * 4 + e;

    const float* __restrict__ sr = scores + (size_t)b * (RLEN * 4) + e;
    const float* __restrict__ gr = gumbel + (size_t)r * RLEN;

    // ---- Single global read: v[s] for positions p = tid + TPB*s; fused max ----
    float v[VPT];
    float lm = -FLT_MAX;
#pragma unroll
    for (int s = 0; s < VPT; ++s) {
        int p = tid + TPB * s;
        float x = sr[(size_t)p * 4] + gr[p];
        v[s] = x;
        lm = fmaxf(lm, x);
    }
    // Pin v[] into VGPRs: forbids rematerialization-from-global (R10: VGPR=64
    // proved the compiler was re-loading v at every use site).
#pragma unroll
    for (int s = 0; s < VPT; ++s) asm volatile("" : "+v"(v[s]));

    // ---- Block max M0 (exact, order-independent) ----
#pragma unroll
    for (int o = 32; o; o >>= 1) lm = fmaxf(lm, __shfl_xor(lm, o));
    if (lane == 0) s_Am[0][wid] = lm;
    __syncthreads();
    float M0 = s_Am[0][0];
#pragma unroll
    for (int w = 1; w < 16; ++w) M0 = fmaxf(M0, s_Am[0][w]);   // uniform
    const float C = M0 * 10.0f;          // anchor for the frozen-tail U only

    // ---- Adaptive theta: exact count from registers, ln-step to ~2048 ----
    // count predicate (v[s] >= theta) is IDENTICAL to the append predicate,
    // so the final cnt equals the accepted count exactly: no overflow path.
    float theta = M0 - THETA_OFF;
    for (int probe = 0; probe < 12; ++probe) {
        int lc = 0;
#pragma unroll
        for (int s = 0; s < VPT; ++s) lc += (v[s] >= theta) ? 1 : 0;
#pragma unroll
        for (int o = 32; o; o >>= 1) lc += __shfl_xor(lc, o);
        if (lane == 0) s_IC[wid] = lc;
        __syncthreads();
        int cc = 0;
#pragma unroll
        for (int w = 0; w < 16; ++w) cc += s_IC[w];        // uniform (int)
        __syncthreads();                 // s_IC reads done before next write
        if (cc > MAXC - 64)      theta += __logf((float)cc) - LN_TGT;  // up
        else if (cc < KSEL)      theta -= LN_TGT - __logf((float)(cc < 1 ? 1 : cc));
        else break;                      // 64 <= cnt <= 8128: accept
    }

    // ---- Collect candidates + frozen-tail Mu/U (from registers) ----
    if (tid == 0) s_cnt = 0;
    __syncthreads();
    {
        float mu = -FLT_MAX, u = 0.f;
#pragma unroll
        for (int s = 0; s < VPT; ++s) {
            float val = v[s];
            if (val >= theta) {
                int sl = atomicAdd(&s_cnt, 1);
                if (sl < MAXC) { cand_idx[sl] = tid + TPB * s; cand_kv[sl] = val; }
            } else {
                mu = fmaxf(mu, val);
                float yv = fmaf(val, 10.f, -C);
                if (yv > -87.f) u += __expf(yv);   // below -87 flushes to 0 anyway
            }
        }
#pragma unroll
        for (int o = 32; o; o >>= 1) {
            mu = fmaxf(mu, __shfl_xor(mu, o));
            u += __shfl_xor(u, o);
        }
        if (lane == 0) { s_EA[wid] = mu; s_EB[wid] = u; }
    }
    __syncthreads();                     // staging + partials visible
    int cnt = s_cnt;
    float Mu = -FLT_MAX, U = 0.f;
#pragma unroll
    for (int w = 0; w < 16; ++w) { Mu = fmaxf(Mu, s_EA[w]); U += s_EB[w]; }
    // v[] is dead past this point (frees 64 VGPRs for the scan); the rare
    // expansion path re-reads global with identical arithmetic.

    // ---- Owner pull: value -> rcur (VGPR); kv slot becomes khot acc = 0 ----
    float rcur[REGS];
#pragma unroll
    for (int j = 0; j < REGS; ++j) {
        int sl = tid + TPB * j;
        if (sl < cnt) {
            rcur[j] = cand_kv[sl];       // appender's write, barrier'd above
            cand_kv[sl] = 0.f;           // same-thread from here on
        } else rcur[j] = 0.f;
    }

    // ---- Fused scan: 64 iterations, ONE barrier each ----
    // anc = anchor for this iteration's sumexp (prev iteration's fresh max;
    // block-uniform, >= all current 10*values -> exp args <= 0).
    bool  noexp = false;
    float anc = C;
    float pa = 0.f, prcp = 0.f, pt2 = 0.f;   // set at end of t=0
    for (int t = 0; t < NITER; ++t) {
        const int pb = t & 1;
        // Phase A+B fused: apply iteration t-1's onehot (gated), track max,
        // and accumulate sumexp at anchor anc in the same pass.
        float lmx = -FLT_MAX, ls = 0.f;
        if (t == 0) {
#pragma unroll
            for (int j = 0; j < REGS; ++j) {
                int sl = tid + TPB * j;
                if (sl < cnt) {
                    float cur = rcur[j];
                    lmx = fmaxf(lmx, cur);
                    ls += __expf(fmaf(cur, 10.f, -anc));
                }
            }
        } else {
#pragma unroll
            for (int j = 0; j < REGS; ++j) {
                int sl = tid + TPB * j;
                if (sl < cnt) {
                    float cur = rcur[j];
                    float y = fmaf(cur, 10.f, -pa);
                    if (y > pt2) {
                        float o = __expf(y) * prcp;
                        cand_kv[sl] += o;               // same-thread LDS RMW
                        cur += __logf(fmaxf(1.f - o, FLT_MIN));
                        rcur[j] = cur;
                    }
                    lmx = fmaxf(lmx, cur);
                    ls += __expf(fmaf(cur, 10.f, -anc));
                }
            }
        }
        // One interleaved butterfly: max and sum chains overlap.
#pragma unroll
        for (int o = 32; o; o >>= 1) {
            lmx = fmaxf(lmx, __shfl_xor(lmx, o));
            ls += __shfl_xor(ls, o);
        }
        if (lane == 0) { s_Am[pb][wid] = lmx; s_Bs[pb][wid] = ls; }
        __syncthreads();                 // THE one barrier of this iteration
        float gm, Ssum;
        {
            const float4* pA = (const float4*)&s_Am[pb][0];
            const float4* pB = (const float4*)&s_Bs[pb][0];
            float4 a0 = pA[0], a1 = pA[1], a2 = pA[2], a3 = pA[3];
            float4 b0 = pB[0], b1 = pB[1], b2 = pB[2], b3 = pB[3];
            gm = fmaxf(fmaxf(fmaxf(a0.x, a0.y), fmaxf(a0.z, a0.w)),
                 fmaxf(fmaxf(fmaxf(a1.x, a1.y), fmaxf(a1.z, a1.w)),
                 fmaxf(fmaxf(fmaxf(a2.x, a2.y), fmaxf(a2.z, a2.w)),
                       fmaxf(fmaxf(a3.x, a3.y), fmaxf(a3.z, a3.w)))));
            Ssum = ((b0.x + b0.y) + (b0.z + b0.w))
                 + ((b1.x + b1.y) + (b1.z + b1.w))
                 + ((b2.x + b2.y) + (b2.z + b2.w))
                 + ((b3.x + b3.y) + (b3.z + b3.w));
        }
        float anext = fmaxf(gm, Mu) * 10.f;   // fresh max (next anchor)
        float aeff  = anc;
        float S     = Ssum;
        // Guard (uniform, rare ~2% of rows once): stale anchor too far above
        // the fresh max -> terms near the new max underflowed; redo at anext.
        // Without this, a >8.7 top-gap (Exp-tail, ~certain somewhere per
        // launch over 256 rows) would collapse S to 0.
        if (anc - anext > AGUARD) {
            float l2 = 0.f;
#pragma unroll
            for (int j = 0; j < REGS; ++j)
                if (tid + TPB * j < cnt) l2 += __expf(fmaf(rcur[j], 10.f, -anext));
#pragma unroll
            for (int o = 32; o; o >>= 1) l2 += __shfl_xor(l2, o);
            if (lane == 0) s_R[wid] = l2;
            __syncthreads();
            S = 0.f;
#pragma unroll
            for (int w = 0; w < 16; ++w) S += s_R[w];
            aeff = anext;
        }
        if (U > 0.f) S += __expf(C - aeff + __logf(U));  // frozen tail, log-space
        float lnse = __logf(S);
        float rcp  = 1.f / S;
        if (tid == 0) { s_mx[t] = aeff; s_rcp[t] = rcp; }  // backfill history
        pa = aeff; prcp = rcp; pt2 = lnse - 18.03f;
        anc = anext;

        // Expansion trigger (uniform): non-candidate onehot_t > 2^-25 requires
        // 10*Mu > Lse_t - 17.33; fire 2.67 early. Lands before iteration t+1
        // applies rcp_t corrections -> exact. Lse is anchor-independent.
        if (!noexp && t < NITER - 1) {
            float Lse = aeff + lnse;
            if (10.f * Mu > Lse - 20.f) {
                float thOld = theta;
                float thN   = (Lse - 26.f) * 0.1f;
                int   oldc  = cnt;
                float mu2 = -FLT_MAX, u2 = 0.f;
#pragma unroll 4
                for (int s = 0; s < VPT; ++s) {
                    int p = tid + TPB * s;
                    float val = sr[(size_t)p * 4] + gr[p];   // bit-identical v
                    if (val < thOld) {
                        if (val >= thN) {
                            int sl = atomicAdd(&s_cnt, 1);
                            if (sl < MAXC) {
                                cand_idx[sl] = p;
                                cand_kv[sl]  = val;   // staged, bit-frozen
                            }
                        } else {
                            mu2 = fmaxf(mu2, val);
                            float yv = fmaf(val, 10.f, -C);
                            if (yv > -87.f) u2 += __expf(yv);
                        }
                    }
                }
#pragma unroll
                for (int o = 32; o; o >>= 1) {
                    mu2 = fmaxf(mu2, __shfl_xor(mu2, o));
                    u2 += __shfl_xor(u2, o);
                }
                if (lane == 0) { s_EA[wid] = mu2; s_EB[wid] = u2; }
                __syncthreads();         // appends + partials visible
                int newc = s_cnt;
                if (newc > MAXC) {
                    if (tid == 0) s_cnt = oldc;  // discard partial appends
                    noexp = true;                // uniform; never expand again
                } else {
                    float m2 = -FLT_MAX, uu = 0.f;
#pragma unroll
                    for (int w = 0; w < 16; ++w) {
                        m2 = fmaxf(m2, s_EA[w]); uu += s_EB[w];
                    }
                    Mu = m2; U = uu; theta = thN;
                    // owners pull new slots: value -> rcur, kv -> khot backfill
#pragma unroll
                    for (int j = 0; j < REGS; ++j) {
                        int sl = tid + TPB * j;
                        if (sl >= oldc && sl < newc) {
                            float vv = cand_kv[sl];
                            rcur[j] = vv;
                            float kb = 0.f;   // onehots tt<t (each < e^-20)
                            for (int tt = 0; tt < t; ++tt)
                                kb += __expf(fmaf(vv, 10.f, -s_mx[tt])) * s_rcp[tt];
                            cand_kv[sl] = kb;
                        }
                    }
                    cnt = newc;
                }
            }
        }
    }
    // final iteration's onehot (t = NITER-1): accumulate only (gated, tiny-skip)
#pragma unroll
    for (int j = 0; j < REGS; ++j) {
        int sl = tid + TPB * j;
        if (sl < cnt) {
            float y = fmaf(rcur[j], 10.f, -pa);
            if (y > pt2) cand_kv[sl] += __expf(y) * prcp;
        }
    }
    __syncthreads();       // all khot final & visible to all threads

    // ---- Radix-histogram top-64 (exact, jax top_k tie-break) ----
    // Keys = __float_as_uint(khot), khot >= 0 -> bit order == value order.
    // kh == 0 slots are excluded (>=64 positive khot guaranteed: the true
    // top-64 each have khot >= 1.5e-5, far above the accumulate gate).
    // Pass bins: [31:21] (2048), [20:10] (2048), [9:0] (1024). After each
    // pass, wave 0 finds the bin holding descending-rank Rrem and the
    // residual rank within it. After pass 3: K* = exact 64th-largest key,
    // Rrem = number of ties (== K*) to take, smallest index first.
    unsigned prefix = 0;
    int Rrem = KSEL;
    for (int pass = 0; pass < 3; ++pass) {
        const int nbins = (pass == 2) ? 1024 : 2048;
        for (int i = tid; i < nbins; i += TPB) s_hist[i] = 0;
        __syncthreads();
#pragma unroll
        for (int j = 0; j < REGS; ++j) {
            int sl = tid + TPB * j;
            if (sl < cnt) {
                unsigned key = __float_as_uint(cand_kv[sl]);
                if (key != 0u) {
                    bool m; int bin;
                    if (pass == 0)      { m = true;                     bin = key >> 21; }
                    else if (pass == 1) { m = (key >> 21) == prefix;    bin = (key >> 10) & 2047; }
                    else                { m = (key >> 10) == prefix;    bin = key & 1023; }
                    if (m) atomicAdd(&s_hist[bin], 1);
                }
            }
        }
        __syncthreads();
        if (wid == 0) {
            int Rl = Rrem, found = -1;
            const int nch = nbins >> 6;
            for (int c = 0; c < nch && found < 0; ++c) {
                int bin = nbins - 1 - (c * 64 + lane);   // descending bins
                int h = s_hist[bin];
                int cum = h;
#pragma unroll
                for (int s2 = 1; s2 < 64; s2 <<= 1) {
                    int vv = __shfl_up(cum, s2);
                    if (lane >= s2) cum += vv;
                }
                unsigned long long mb = __ballot(cum >= Rl);
                if (mb) {
                    int fl = __ffsll(mb) - 1;            // first (highest) bin
                    int cumex = __shfl(cum, fl) - __shfl(h, fl);
                    found = nbins - 1 - (c * 64 + fl);
                    Rl -= cumex;                          // rank inside bin
                } else {
                    Rl -= __shfl(cum, 63);                // whole chunk above
                }
            }
            if (lane == 0) { s_selB = found; s_selR = Rl; }
        }
        __syncthreads();
        prefix = (prefix << ((pass == 2) ? 10 : 11)) | (unsigned)s_selB;
        Rrem = s_selR;
    }
    const unsigned Kstar = prefix;       // exact 64th-largest key
    const int need = Rrem;               // ties to take (>= 1)

    // ---- Emit: all key > K*; collect ties == K* ----
    if (tid == 0) s_tcnt = 0;
    __syncthreads();
#pragma unroll
    for (int j = 0; j < REGS; ++j) {
        int sl = tid + TPB * j;
        if (sl < cnt) {
            float kh = cand_kv[sl];
            unsigned key = __float_as_uint(kh);
            if (key > Kstar) {
                int p = cand_idx[sl];
                out[((size_t)b * RLEN + (size_t)p) * 4 + e] = (1.f - kh) + kh;
            } else if (key == Kstar) {
                int tp = atomicAdd(&s_tcnt, 1);
                if (tp < TCAP) s_tie[tp] = cand_idx[sl];
            }
        }
    }
    __syncthreads();
    // wave 0 picks the `need` smallest tie indices (typically need==1, T==1)
    if (wid == 0) {
        int T = s_tcnt < TCAP ? s_tcnt : TCAP;
        float kv = __uint_as_float(Kstar);
        float ov = (1.f - kv) + kv;
        for (int rdone = 0; rdone < need; ++rdone) {
            int bi = 0x7fffffff, bp = -1;
            for (int i = lane; i < T; i += 64) {
                int vv = s_tie[i];
                if (vv < bi) { bi = vv; bp = i; }
            }
#pragma unroll
            for (int s2 = 32; s2; s2 >>= 1) {
                int oi = __shfl_xor(bi, s2);
                int op = __shfl_xor(bp, s2);
                if (oi < bi) { bi = oi; bp = op; }
            }
            if (lane == 0 && bi != 0x7fffffff) {
                out[((size_t)b * RLEN + (size_t)bi) * 4 + e] = ov;
                s_tie[bp] = 0x7fffffff;      // remove; wave-local LDS is ordered
            }
        }
    }
}

extern "C" void kernel_launch(void* const* d_in, const int* in_sizes, int n_in,
                              void* d_out, int out_size, void* d_ws, size_t ws_size,
                              hipStream_t stream) {
    const float* scores = (const float*)d_in[0];   // [B=64, N=256, N=256, E=4] f32
    const float* gumbel = (const float*)d_in[1];   // [B*E=256, N*N=65536] f32
    float* out = (float*)d_out;                    // [B, N, N, E] f32

    // DMA zero-fill (graph-capturable async memset), then sparse scatter.
    hipMemsetAsync(d_out, 0, (size_t)out_size * sizeof(float), stream);
    GumbelSampler_2482491097709_kernel<<<NROW, TPB, 0, stream>>>(scores, gumbel, out);
}

// Round 4
// 343.656 us; speedup vs baseline: 1.3901x; 1.0756x over previous
//
#include <hip/hip_runtime.h>
#include <cfloat>

#define NROW   256      // B*E rows
#define RLEN   65536    // N*N elements per row
#define TPB    1024
#define VPT    64       // register-resident values per thread (64*1024 = RLEN)
#define REGS   8        // candidate slots per thread (values in VGPRs)
#define MAXC   (TPB*REGS)   // 8192
#define NITER  64       // scan length (local_k)
#define KSEL   64       // top-k
#define THETA_OFF 8.0f  // initial candidate threshold: M0 - 8.0
#define TCAP   256      // tie-list capacity
#define LN_TGT 7.6246f  // ln(2048): adaptive-theta target count
#define GATE  (-18.03f) // onehot significance gate: 10v - Lse > -18.03

// R12 (resubmit; round-3 bench died to container infra, no counter evidence
// of a kernel defect; audited: uniform barriers, bounded loops, guarded LDS).
// R12 = R11 with the per-iteration MAX reduction deleted (the scan's DS-pipe
// and critical-path dominator):
// (1) Lse-anchored scan: anchor the sumexp at the PREVIOUS log-sum-exp
//     (anc = Lse_{t-1}). Then onehot_t = exp(10v - Lse_t) directly (no rcp),
//     Lse_t = anc + ln(S_t) is the exact LSE for ANY anchor, and
//     Lse >= 10*max always => exp args <= 0, no overflow, no stale-anchor
//     guard needed (R11's AGUARD path deleted). Terms below e^-87 flush to
//     zero = harmless (< e^-76 relative; U-tail term ~e^-74 keeps S > 0,
//     and the expansion trigger catches any mass below theta — unchanged).
//     Gate y > lnse-18.03 becomes the CONSTANT y > -18.03 (same semantics).
//     Backfill history shrinks to one array s_Lse[t].
// (2) Cheap cross-wave reduce: lanes read s_P[lane&15] (one conflict-free
//     ds_read_b32) + 4-step shfl, replacing 8x ds_read_b128 + 31 serial
//     VALU ops per thread per iteration. DS instrs/wave/iter: 22 -> 12.
// (3) Warp-aggregated candidate append (ballot + one atomic per wave-iter)
//     replaces ~2048 serialized same-address LDS atomics in collect.
// (4) Radix pass 0 starts at chunk 23: khot <= 64(1+eps) => key < bits(80.0)
//     => bins 576..2047 provably empty; skips ~24 serial wave-0 scan rounds.
// Everything else (adaptive theta, expansion net, radix select, tie-break
// emit) structurally unchanged. LDS ~83.5 KB keeps 1 block/CU.
__global__ void __launch_bounds__(TPB, 4)
GumbelSampler_2482491097709_kernel(const float* __restrict__ scores,
                                   const float* __restrict__ gumbel,
                                   float* __restrict__ out)
{
    __shared__ float s_P[2][16];    // scan sum partials (ping-pong)
    __shared__ float s_EA[16];      // collect/expansion max partials
    __shared__ float s_EB[16];      // collect/expansion sum partials
    __shared__ int   s_IC[16];      // adaptive-theta count partials
    __shared__ float s_Lse[NITER];  // recorded Lse_t (for backfill)
    __shared__ int   s_cnt;
    __shared__ int   s_selB;        // histogram: found bin (per pass)
    __shared__ int   s_selR;        // histogram: residual rank (per pass)
    __shared__ int   s_tcnt;
    __shared__ int   s_tie[TCAP];
    __shared__ int   s_hist[4096];  // 16 KB: radix passes use <=2048 bins;
                                    // oversized on purpose (LDS > 80 KB)
    __shared__ int   cand_idx[MAXC];
    __shared__ float cand_kv[MAXC]; // staging value, then accumulated khot

    const int tid  = threadIdx.x;
    const int lane = tid & 63;
    const int wid  = tid >> 6;

    // XCD swizzle: co-locate the 4 e-blocks of each b on one XCD (perf only).
    const int q    = blockIdx.x;
    const int xcd  = q & 7;
    const int slot = q >> 3;
    const int b    = xcd * 8 + (slot & 7);
    const int e    = slot >> 3;
    const int r    = b * 4 + e;

    const float* __restrict__ sr = scores + (size_t)b * (RLEN * 4) + e;
    const float* __restrict__ gr = gumbel + (size_t)r * RLEN;

    // ---- Single global read: v[s] for positions p = tid + TPB*s; fused max ----
    float v[VPT];
    float lm = -FLT_MAX;
#pragma unroll
    for (int s = 0; s < VPT; ++s) {
        int p = tid + TPB * s;
        float x = sr[(size_t)p * 4] + gr[p];
        v[s] = x;
        lm = fmaxf(lm, x);
    }
    // Pin v[] into registers (VGPR/AGPR): forbids rematerialization-from-global.
#pragma unroll
    for (int s = 0; s < VPT; ++s) asm volatile("" : "+v"(v[s]));

    // ---- Block max M0 (exact, order-independent; uniform in all lanes) ----
#pragma unroll
    for (int o = 32; o; o >>= 1) lm = fmaxf(lm, __shfl_xor(lm, o));
    if (lane == 0) s_P[0][wid] = lm;
    __syncthreads();
    float M0 = s_P[0][lane & 15];
#pragma unroll
    for (int o = 8; o; o >>= 1) M0 = fmaxf(M0, __shfl_xor(M0, o));
    const float C = M0 * 10.0f;          // anchor for the frozen-tail U only

    // ---- Adaptive theta: exact count from registers, ln-step to ~2048 ----
    // count predicate (v[s] >= theta) is IDENTICAL to the append predicate,
    // so the final cnt equals the accepted count exactly: no overflow path.
    float theta = M0 - THETA_OFF;
    for (int probe = 0; probe < 12; ++probe) {
        int lc = 0;
#pragma unroll
        for (int s = 0; s < VPT; ++s) lc += (v[s] >= theta) ? 1 : 0;
#pragma unroll
        for (int o = 32; o; o >>= 1) lc += __shfl_xor(lc, o);
        if (lane == 0) s_IC[wid] = lc;
        __syncthreads();
        int cc = s_IC[lane & 15];
#pragma unroll
        for (int o = 8; o; o >>= 1) cc += __shfl_xor(cc, o);   // uniform
        __syncthreads();                 // s_IC reads done before next write
        if (cc > MAXC - 64)      theta += __logf((float)cc) - LN_TGT;  // up
        else if (cc < KSEL)      theta -= LN_TGT - __logf((float)(cc < 1 ? 1 : cc));
        else break;                      // 64 <= cnt <= 8128: accept
    }

    // ---- Collect candidates + frozen-tail Mu/U (from registers) ----
    // Warp-aggregated append: one LDS atomic per wave-iteration instead of
    // one serialized same-address atomic per candidate.
    if (tid == 0) s_cnt = 0;
    __syncthreads();
    {
        float mu = -FLT_MAX, u = 0.f;
#pragma unroll
        for (int s = 0; s < VPT; ++s) {
            float val = v[s];
            bool pr = (val >= theta);
            unsigned long long m = __ballot(pr);
            if (pr) {
                int lead = __ffsll(m) - 1;
                int base = 0;
                if (lane == lead) base = atomicAdd(&s_cnt, (int)__popcll(m));
                base = __shfl(base, lead);
                int sl = base + (int)__popcll(m & ((1ull << lane) - 1ull));
                if (sl < MAXC) { cand_idx[sl] = tid + TPB * s; cand_kv[sl] = val; }
            } else {
                mu = fmaxf(mu, val);
                float yv = fmaf(val, 10.f, -C);
                if (yv > -87.f) u += __expf(yv);   // below -87 flushes anyway
            }
        }
#pragma unroll
        for (int o = 32; o; o >>= 1) {
            mu = fmaxf(mu, __shfl_xor(mu, o));
            u += __shfl_xor(u, o);
        }
        if (lane == 0) { s_EA[wid] = mu; s_EB[wid] = u; }
    }
    __syncthreads();                     // staging + partials visible
    int cnt = s_cnt;
    float Mu = s_EA[lane & 15], U = s_EB[lane & 15];
#pragma unroll
    for (int o = 8; o; o >>= 1) {
        Mu = fmaxf(Mu, __shfl_xor(Mu, o));
        U += __shfl_xor(U, o);
    }
    // v[] is dead past this point (frees registers for the scan); the rare
    // expansion path re-reads global with identical arithmetic.

    // ---- Owner pull: value -> rcur (VGPR); kv slot becomes khot acc = 0 ----
    float rcur[REGS];
#pragma unroll
    for (int j = 0; j < REGS; ++j) {
        int sl = tid + TPB * j;
        if (sl < cnt) {
            rcur[j] = cand_kv[sl];       // appender's write, barrier'd above
            cand_kv[sl] = 0.f;           // same-thread from here on
        } else rcur[j] = 0.f;
    }

    // ---- Lse-anchored scan: 64 iterations, ONE barrier, NO max reduce ----
    // anc = Lse_{t-1} (uniform). onehot_{t-1} = exp(10v - anc); this
    // iteration's sumexp is anchored at anc too; Lse_t = anc + ln(S_t) is
    // the exact total LSE (anchor-independent identity). Lse >= 10*max
    // always => exp args <= 0.
    bool  noexp = false;
    float anc = C;                       // t=0 anchor: C = 10*M0 >= 10*max
    for (int t = 0; t < NITER; ++t) {
        const int pb = t & 1;
        float ls = 0.f;
        if (t == 0) {
#pragma unroll
            for (int j = 0; j < REGS; ++j)
                if (tid + TPB * j < cnt)
                    ls += __expf(fmaf(rcur[j], 10.f, -anc));
        } else {
#pragma unroll
            for (int j = 0; j < REGS; ++j) {
                int sl = tid + TPB * j;
                if (sl < cnt) {
                    float cur = rcur[j];
                    float y = fmaf(cur, 10.f, -anc);
                    float e_ = __expf(y);          // = onehot_{t-1}
                    if (y > GATE) {
                        cand_kv[sl] += e_;         // same-thread LDS RMW
                        cur += __logf(fmaxf(1.f - e_, FLT_MIN));
                        rcur[j] = cur;
                        e_ = __expf(fmaf(cur, 10.f, -anc));  // post-update term
                    }
                    ls += e_;
                }
            }
        }
#pragma unroll
        for (int o = 32; o; o >>= 1) ls += __shfl_xor(ls, o);
        if (lane == 0) s_P[pb][wid] = ls;
        __syncthreads();                 // THE one barrier of this iteration
        float S = s_P[pb][lane & 15];    // conflict-free b32 (16 addrs, bcast)
#pragma unroll
        for (int o = 8; o; o >>= 1) S += __shfl_xor(S, o);   // uniform
        if (U > 0.f) S += __expf(C - anc + __logf(U));  // frozen tail
        float Lse = anc + __logf(S);
        if (tid == 0) s_Lse[t] = Lse;    // backfill history

        // Expansion trigger (uniform): non-candidate onehot_t > 2^-25 needs
        // 10*Mu > Lse_t - 17.33; fire 2.67 early. Lands before iteration t+1
        // applies onehot_t -> exact.
        if (!noexp && t < NITER - 1 && 10.f * Mu > Lse - 20.f) {
            float thOld = theta;
            float thN   = (Lse - 26.f) * 0.1f;
            int   oldc  = cnt;
            float mu2 = -FLT_MAX, u2 = 0.f;
#pragma unroll 4
            for (int s = 0; s < VPT; ++s) {
                int p = tid + TPB * s;
                float val = sr[(size_t)p * 4] + gr[p];   // bit-identical v
                if (val < thOld) {
                    if (val >= thN) {
                        int sl = atomicAdd(&s_cnt, 1);
                        if (sl < MAXC) {
                            cand_idx[sl] = p;
                            cand_kv[sl]  = val;   // staged, bit-frozen
                        }
                    } else {
                        mu2 = fmaxf(mu2, val);
                        float yv = fmaf(val, 10.f, -C);
                        if (yv > -87.f) u2 += __expf(yv);
                    }
                }
            }
#pragma unroll
            for (int o = 32; o; o >>= 1) {
                mu2 = fmaxf(mu2, __shfl_xor(mu2, o));
                u2 += __shfl_xor(u2, o);
            }
            if (lane == 0) { s_EA[wid] = mu2; s_EB[wid] = u2; }
            __syncthreads();             // appends + partials visible
            int newc = s_cnt;
            if (newc > MAXC) {
                if (tid == 0) s_cnt = oldc;  // discard partial appends
                noexp = true;                // uniform; never expand again
            } else {
                float m2 = s_EA[lane & 15], uu = s_EB[lane & 15];
#pragma unroll
                for (int o = 8; o; o >>= 1) {
                    m2 = fmaxf(m2, __shfl_xor(m2, o));
                    uu += __shfl_xor(uu, o);
                }
                Mu = m2; U = uu; theta = thN;
                // owners pull new slots: value -> rcur, kv -> khot backfill
#pragma unroll
                for (int j = 0; j < REGS; ++j) {
                    int sl = tid + TPB * j;
                    if (sl >= oldc && sl < newc) {
                        float vv = cand_kv[sl];
                        rcur[j] = vv;
                        float kb = 0.f;   // onehots tt<t (each < e^-20)
                        for (int tt = 0; tt < t; ++tt)
                            kb += __expf(fmaf(vv, 10.f, -s_Lse[tt]));
                        cand_kv[sl] = kb;
                    }
                }
                cnt = newc;
            }
        }
        anc = Lse;                       // next iteration's anchor
    }
    // final iteration's onehot (t = NITER-1): accumulate only (gated)
#pragma unroll
    for (int j = 0; j < REGS; ++j) {
        int sl = tid + TPB * j;
        if (sl < cnt) {
            float y = fmaf(rcur[j], 10.f, -anc);
            if (y > GATE) cand_kv[sl] += __expf(y);
        }
    }
    __syncthreads();       // all khot final & visible to all threads

    // ---- Radix-histogram top-64 (exact, jax top_k tie-break) ----
    // Keys = __float_as_uint(khot), khot >= 0 -> bit order == value order.
    // kh == 0 slots are excluded (>=64 positive khot guaranteed: the true
    // top-64 each have khot >= 1.5e-5, far above the accumulate gate).
    // Pass bins: [31:21] (2048), [20:10] (2048), [9:0] (1024). After each
    // pass, wave 0 finds the bin holding descending-rank Rrem and the
    // residual rank within it. After pass 3: K* = exact 64th-largest key,
    // Rrem = number of ties (== K*) to take, smallest index first.
    unsigned prefix = 0;
    int Rrem = KSEL;
    for (int pass = 0; pass < 3; ++pass) {
        const int nbins = (pass == 2) ? 1024 : 2048;
        for (int i = tid; i < nbins; i += TPB) s_hist[i] = 0;
        __syncthreads();
#pragma unroll
        for (int j = 0; j < REGS; ++j) {
            int sl = tid + TPB * j;
            if (sl < cnt) {
                unsigned key = __float_as_uint(cand_kv[sl]);
                if (key != 0u) {
                    bool m; int bin;
                    if (pass == 0)      { m = true;                     bin = key >> 21; }
                    else if (pass == 1) { m = (key >> 21) == prefix;    bin = (key >> 10) & 2047; }
                    else                { m = (key >> 10) == prefix;    bin = key & 1023; }
                    if (m) atomicAdd(&s_hist[bin], 1);
                }
            }
        }
        __syncthreads();
        if (wid == 0) {
            int Rl = Rrem, found = -1;
            const int nch = nbins >> 6;
            // pass 0: khot <= 64(1+eps) => key < bits(80.f) => bins >= 576
            // empty; skip chunks 0..22 (bins 2047..576) of the serial scan.
            const int c0 = (pass == 0) ? 23 : 0;
            for (int c = c0; c < nch && found < 0; ++c) {
                int bin = nbins - 1 - (c * 64 + lane);   // descending bins
                int h = s_hist[bin];
                int cum = h;
#pragma unroll
                for (int s2 = 1; s2 < 64; s2 <<= 1) {
                    int vv = __shfl_up(cum, s2);
                    if (lane >= s2) cum += vv;
                }
                unsigned long long mb = __ballot(cum >= Rl);
                if (mb) {
                    int fl = __ffsll(mb) - 1;            // first (highest) bin
                    int cumex = __shfl(cum, fl) - __shfl(h, fl);
                    found = nbins - 1 - (c * 64 + fl);
                    Rl -= cumex;                          // rank inside bin
                } else {
                    Rl -= __shfl(cum, 63);                // whole chunk above
                }
            }
            if (lane == 0) { s_selB = found; s_selR = Rl; }
        }
        __syncthreads();
        prefix = (prefix << ((pass == 2) ? 10 : 11)) | (unsigned)s_selB;
        Rrem = s_selR;
    }
    const unsigned Kstar = prefix;       // exact 64th-largest key
    const int need = Rrem;               // ties to take (>= 1)

    // ---- Emit: all key > K*; collect ties == K* ----
    if (tid == 0) s_tcnt = 0;
    __syncthreads();
#pragma unroll
    for (int j = 0; j < REGS; ++j) {
        int sl = tid + TPB * j;
        if (sl < cnt) {
            float kh = cand_kv[sl];
            unsigned key = __float_as_uint(kh);
            if (key > Kstar) {
                int p = cand_idx[sl];
                out[((size_t)b * RLEN + (size_t)p) * 4 + e] = (1.f - kh) + kh;
            } else if (key == Kstar) {
                int tp = atomicAdd(&s_tcnt, 1);
                if (tp < TCAP) s_tie[tp] = cand_idx[sl];
            }
        }
    }
    __syncthreads();
    // wave 0 picks the `need` smallest tie indices (typically need==1, T==1)
    if (wid == 0) {
        int T = s_tcnt < TCAP ? s_tcnt : TCAP;
        float kv = __uint_as_float(Kstar);
        float ov = (1.f - kv) + kv;
        for (int rdone = 0; rdone < need; ++rdone) {
            int bi = 0x7fffffff, bp = -1;
            for (int i = lane; i < T; i += 64) {
                int vv = s_tie[i];
                if (vv < bi) { bi = vv; bp = i; }
            }
#pragma unroll
            for (int s2 = 32; s2; s2 >>= 1) {
                int oi = __shfl_xor(bi, s2);
                int op = __shfl_xor(bp, s2);
                if (oi < bi) { bi = oi; bp = op; }
            }
            if (lane == 0 && bi != 0x7fffffff) {
                out[((size_t)b * RLEN + (size_t)bi) * 4 + e] = ov;
                s_tie[bp] = 0x7fffffff;      // remove; wave-local LDS is ordered
            }
        }
    }
}

extern "C" void kernel_launch(void* const* d_in, const int* in_sizes, int n_in,
                              void* d_out, int out_size, void* d_ws, size_t ws_size,
                              hipStream_t stream) {
    const float* scores = (const float*)d_in[0];   // [B=64, N=256, N=256, E=4] f32
    const float* gumbel = (const float*)d_in[1];   // [B*E=256, N*N=65536] f32
    float* out = (float*)d_out;                    // [B, N, N, E] f32

    // DMA zero-fill (graph-capturable async memset), then sparse scatter.
    hipMemsetAsync(d_out, 0, (size_t)out_size * sizeof(float), stream);
    GumbelSampler_2482491097709_kernel<<<NROW, TPB, 0, stream>>>(scores, gumbel, out);
}